// Round 3
// baseline (1223.717 us; speedup 1.0000x reference)
//
#include <hip/hip_runtime.h>
#include <stdint.h>

// ---------- helpers ----------
__device__ inline float bf2f(unsigned short u) { return __uint_as_float(((unsigned int)u) << 16); }
__device__ inline unsigned short f2bf(float f) {
    unsigned int x = __float_as_uint(f);
    unsigned int r = x + 0x7fffu + ((x >> 16) & 1u);   // RNE
    return (unsigned short)(r >> 16);
}

typedef __attribute__((ext_vector_type(8))) short bf16x8;
typedef __attribute__((ext_vector_type(4))) float f32x4;
typedef __attribute__((ext_vector_type(4))) int   v4i;

// ---------- MFMA GEMM: C[M,N] = A[M,K] * Bt[N,K]^T (A,Bt bf16) ----------
// mode 0: store bf16. mode 2: store f32 (with rowMap scatter).
// Mdev: if non-null, M read from device. rowOff: global row of A's row 0.
__global__ __launch_bounds__(256) void gemm_bt(
    const unsigned short* __restrict__ A,
    const unsigned short* __restrict__ Bt,
    void* __restrict__ C,
    const int* __restrict__ Mdev,
    const int* __restrict__ rowMap,
    int M, int N, int K, int lda, int ldb, int ldc, int mode, int rowOff)
{
    if (Mdev) M = *Mdev;
    int mt = blockIdx.x, nt = blockIdx.y;
    if (rowOff + mt * 128 >= M) return;

    __shared__ __align__(16) unsigned short As[128 * 64];
    __shared__ __align__(16) unsigned short Bs[128 * 64];

    int tid  = threadIdx.x;
    int lane = tid & 63, wave = tid >> 6;
    int wRow = (wave >> 1) * 64, wCol = (wave & 1) * 64;
    int mBase = mt * 128, nBase = nt * 128;
    int lm = lane & 15, kg = lane >> 4;
    int sr = tid >> 3;          // staging row (0..31)
    int sc = (tid & 7) * 8;     // staging col element

    f32x4 acc[4][4] = {};

    for (int k0 = 0; k0 < K; k0 += 64) {
        __syncthreads();
#pragma unroll
        for (int i = 0; i < 4; ++i) {
            int r = sr + 32 * i;
            int gm = rowOff + mBase + r; if (gm > M - 1) gm = M - 1;
            *(v4i*)&As[r * 64 + sc] = *(const v4i*)&A[(size_t)(gm - rowOff) * lda + k0 + sc];
            int gn = nBase + r; if (gn > N - 1) gn = N - 1;
            *(v4i*)&Bs[r * 64 + sc] = *(const v4i*)&Bt[(size_t)gn * ldb + k0 + sc];
        }
        __syncthreads();
#pragma unroll
        for (int ks = 0; ks < 2; ++ks) {
            bf16x8 af[4], bfr[4];
#pragma unroll
            for (int i = 0; i < 4; ++i) {
                af[i]  = *(const bf16x8*)&As[(wRow + i * 16 + lm) * 64 + ks * 32 + kg * 8];
                bfr[i] = *(const bf16x8*)&Bs[(wCol + i * 16 + lm) * 64 + ks * 32 + kg * 8];
            }
#pragma unroll
            for (int mi = 0; mi < 4; ++mi)
#pragma unroll
                for (int ni = 0; ni < 4; ++ni)
                    acc[mi][ni] = __builtin_amdgcn_mfma_f32_16x16x32_bf16(
                        af[mi], bfr[ni], acc[mi][ni], 0, 0, 0);
        }
    }

    int rbase = (lane >> 4) * 4;
#pragma unroll
    for (int mi = 0; mi < 4; ++mi) {
#pragma unroll
        for (int r = 0; r < 4; ++r) {
            int m = rowOff + mBase + wRow + mi * 16 + rbase + r;
            if (m >= M) continue;
            size_t crow = rowMap ? (size_t)rowMap[m] * ldc : (size_t)(m - rowOff) * ldc;
#pragma unroll
            for (int ni = 0; ni < 4; ++ni) {
                int n = nBase + wCol + ni * 16 + lm;
                if (n >= N) continue;
                float v = acc[mi][ni][r];
                if (mode == 2) ((float*)C)[crow + n] = v;
                else           ((unsigned short*)C)[crow + n] = f2bf(v);
            }
        }
    }
}

// ---------- f32 -> bf16 cast ----------
__global__ void cast_bf16(const float* __restrict__ in, unsigned short* __restrict__ out, int n)
{
    int i = blockIdx.x * 256 + threadIdx.x;
    if (i < n) out[i] = f2bf(in[i]);
}

// ---------- f32 [rows,cols] -> bf16 [rows,ldo] (dest pre-zeroed) ----------
__global__ void cast_pad(const float* __restrict__ in, unsigned short* __restrict__ out,
                         int rows, int cols, int ldo)
{
    int idx = blockIdx.x * 256 + threadIdx.x;
    if (idx < rows * cols) out[(size_t)(idx / cols) * ldo + (idx % cols)] = f2bf(in[idx]);
}

// ---------- transpose+cast: f32 in[R,C] -> bf16 out[C,R] ----------
__global__ void transpose_cast(const float* __restrict__ in, unsigned short* __restrict__ out,
                               int R, int Ccols)
{
    __shared__ float tile[32][33];
    int c0 = blockIdx.x * 32, r0 = blockIdx.y * 32;
    int tx = threadIdx.x, ty = threadIdx.y;
#pragma unroll
    for (int i = 0; i < 4; ++i) {
        int r = r0 + ty + i * 8, c = c0 + tx;
        if (r < R && c < Ccols) tile[ty + i * 8][tx] = in[(size_t)r * Ccols + c];
    }
    __syncthreads();
#pragma unroll
    for (int i = 0; i < 4; ++i) {
        int orow = c0 + ty + i * 8;   // C-dim index
        int ocol = r0 + tx;           // R-dim index
        if (orow < Ccols && ocol < R) out[(size_t)orow * R + ocol] = f2bf(tile[tx][ty + i * 8]);
    }
}

// ---------- fused h1 GEMM + partial bio logits (all f32 VALU) ----------
// A = hidden [32768,768], W = w1 [768,768], part[12][32768][3]:
// part[by][t][c] = sum_{h in by-block} relu( (A@W)[t,h] + b1[h] ) * w2[h][c]
__global__ __launch_bounds__(256) void h1_bio_gemm(
    const float* __restrict__ A, const float* __restrict__ W,
    const float* __restrict__ b1, const float* __restrict__ w2,
    float* __restrict__ part)
{
    __shared__ float AsT[16][64];   // [k][m]
    __shared__ float Ws[16][64];    // [k][n]
    int tx = threadIdx.x, ty = threadIdx.y;
    int tid = ty * 16 + tx;
    int m0 = blockIdx.x * 64, n0 = blockIdx.y * 64;
    float acc[4][4] = {};

    for (int k0 = 0; k0 < 768; k0 += 16) {
        __syncthreads();
        {   // stage A-tile transposed: 64 rows x 16 k
            int row = tid >> 2, seg = (tid & 3) * 4;
            float4 v = *(const float4*)&A[(size_t)(m0 + row) * 768 + k0 + seg];
            AsT[seg + 0][row] = v.x; AsT[seg + 1][row] = v.y;
            AsT[seg + 2][row] = v.z; AsT[seg + 3][row] = v.w;
        }
        {   // stage W-tile: 16 k x 64 n
            int row = tid >> 4, seg = (tid & 15) * 4;
            *(float4*)&Ws[row][seg] = *(const float4*)&W[(size_t)(k0 + row) * 768 + n0 + seg];
        }
        __syncthreads();
#pragma unroll
        for (int kk = 0; kk < 16; ++kk) {
            float4 av = *(const float4*)&AsT[kk][ty * 4];
            float4 bv = *(const float4*)&Ws[kk][tx * 4];
            float a[4] = {av.x, av.y, av.z, av.w};
            float b[4] = {bv.x, bv.y, bv.z, bv.w};
#pragma unroll
            for (int i = 0; i < 4; ++i)
#pragma unroll
                for (int j = 0; j < 4; ++j)
                    acc[i][j] += a[i] * b[j];
        }
    }

    // epilogue: relu(h1 + b1) dotted with w2 cols, partial over this n-block
    float b1v[4], w2l[4][3];
#pragma unroll
    for (int j = 0; j < 4; ++j) {
        int n = n0 + tx * 4 + j;
        b1v[j] = b1[n];
#pragma unroll
        for (int c = 0; c < 3; ++c) w2l[j][c] = w2[n * 3 + c];
    }
    float p[4][3] = {};
#pragma unroll
    for (int i = 0; i < 4; ++i)
#pragma unroll
        for (int j = 0; j < 4; ++j) {
            float v = acc[i][j] + b1v[j];
            v = fmaxf(v, 0.f);
#pragma unroll
            for (int c = 0; c < 3; ++c) p[i][c] += v * w2l[j][c];
        }
    // reduce over tx (16 consecutive lanes share a ty)
#pragma unroll
    for (int i = 0; i < 4; ++i)
#pragma unroll
        for (int c = 0; c < 3; ++c) {
            float s = p[i][c];
            s += __shfl_down(s, 8);
            s += __shfl_down(s, 4);
            s += __shfl_down(s, 2);
            s += __shfl_down(s, 1);
            p[i][c] = s;
        }
    if (tx == 0) {
#pragma unroll
        for (int i = 0; i < 4; ++i) {
            int t = m0 + ty * 4 + i;
#pragma unroll
            for (int c = 0; c < 3; ++c)
                part[(size_t)blockIdx.y * 98304 + (size_t)t * 3 + c] = p[i][c];
        }
    }
}

// ---------- bio finalize: sum 12 partials, log_softmax, argmax ----------
__global__ void bio_final(const float* __restrict__ part, const float* __restrict__ b2,
                          float* __restrict__ out0, int* __restrict__ predLab)
{
    int t = blockIdx.x * 256 + threadIdx.x;
    double a[3] = {(double)b2[0], (double)b2[1], (double)b2[2]};
#pragma unroll
    for (int i = 0; i < 12; ++i)
#pragma unroll
        for (int c = 0; c < 3; ++c)
            a[c] += (double)part[(size_t)i * 98304 + (size_t)t * 3 + c];
    double mx = a[0]; if (a[1] > mx) mx = a[1]; if (a[2] > mx) mx = a[2];
    double ls = mx + log(exp(a[0] - mx) + exp(a[1] - mx) + exp(a[2] - mx));
    out0[t * 3 + 0] = (float)(a[0] - ls);
    out0[t * 3 + 1] = (float)(a[1] - ls);
    out0[t * 3 + 2] = (float)(a[2] - ls);
    int pbest = 0; double bv = a[0];
    if (a[1] > bv) { bv = a[1]; pbest = 1; }
    if (a[2] > bv) { bv = a[2]; pbest = 2; }
    predLab[t] = pbest;
}

// ---------- segmentation pipeline ----------
// meta: [0]=numB  [1]=K(#nonzero)  [2]=idx0(stream pos of first B)
__global__ void seg_init(int* segCount, int* segFirst, int* meta)
{
    int i = blockIdx.x * 256 + threadIdx.x;
    segCount[i] = 0;
    segFirst[i] = 0x7fffffff;
    if (i == 0) meta[2] = 0x7fffffff;
}

__global__ __launch_bounds__(1024) void seg_scan(
    const int* __restrict__ lab, int* __restrict__ streamTok,
    int* __restrict__ cumArr, int* __restrict__ meta)
{
    __shared__ int sM[1024], sB[1024];
    int t = threadIdx.x;
    int base = t * 32;
    int mc = 0, bc = 0;
    for (int i = 0; i < 32; ++i) { int v = lab[base + i]; mc += (v != 0); bc += (v == 1); }
    sM[t] = mc; sB[t] = bc; __syncthreads();
    for (int off = 1; off < 1024; off <<= 1) {
        int vm = 0, vb = 0;
        if (t >= off) { vm = sM[t - off]; vb = sB[t - off]; }
        __syncthreads();
        sM[t] += vm; sB[t] += vb;
        __syncthreads();
    }
    int mBase = sM[t] - mc, bBase = sB[t] - bc;
    int mRun = 0, bRun = 0;
    for (int i = 0; i < 32; ++i) {
        int v = lab[base + i];
        if (v != 0) {
            int q = mBase + mRun;
            streamTok[q] = base + i;
            int isB = (v == 1);
            cumArr[q] = bBase + bRun + isB;
            if (isB && (bBase + bRun) == 0) meta[2] = q;   // globally-first B (unique)
            mRun += 1; bRun += isB;
        }
    }
    if (t == 1023) { meta[0] = sB[1023]; meta[1] = sM[1023]; }
}

__global__ void row_count(const int* __restrict__ lab, int* __restrict__ rowC)
{
    __shared__ int red[256];
    int b = blockIdx.x, t = threadIdx.x;
    int cnt = 0;
    for (int j = t; j < 512; j += 256) cnt += (lab[b * 512 + j] == 1);
    red[t] = cnt; __syncthreads();
    for (int st = 128; st > 0; st >>= 1) { if (t < st) red[t] += red[t + st]; __syncthreads(); }
    if (t == 0) rowC[b] = red[0];
}

__global__ void seg_finalize(const int* __restrict__ rowC, int* __restrict__ rowStart,
                             int* __restrict__ meta)
{
    if (threadIdx.x == 0 && blockIdx.x == 0) {
        if (meta[2] == 0x7fffffff) meta[2] = 0;
        int acc = 0;
        for (int b = 0; b < 64; ++b) { rowStart[b] = acc; acc += rowC[b]; }
    }
}

__global__ void build_map(const int* __restrict__ rowC, const int* __restrict__ rowStart,
                          int* __restrict__ map)
{
    int b = blockIdx.x;
    int c = rowC[b], s0 = rowStart[b];
    for (int j = threadIdx.x; j < c; j += 256) map[s0 + j] = b * 512 + j;
}

__global__ void seg_assign(const int* __restrict__ cumArr, int* __restrict__ segCount,
                           int* __restrict__ segFirst, const int* __restrict__ meta)
{
    int q = blockIdx.x * 256 + threadIdx.x;
    int K = meta[1];
    if (q >= K) return;
    int numB = meta[0], idx0 = meta[2];
    int qq = q + idx0;
    int cumv = (qq < K) ? cumArr[qq] : numB;   // cum is flat numB past the stream end
    int seg = cumv - 1;
    if (seg >= 0) {
        atomicAdd(&segCount[seg], 1);
        atomicMin(&segFirst[seg], q);
    }
}

// means for segments [s0, s0+4096) -> bf16 chunk buffer rows [0,4096)
__global__ __launch_bounds__(256) void seg_means(
    const float* __restrict__ hidden, const int* __restrict__ streamTok,
    const int* __restrict__ segCount, const int* __restrict__ segFirst,
    const int* __restrict__ meta, unsigned short* __restrict__ means, int s0)
{
    int s = s0 + blockIdx.x;
    if (s >= meta[0]) return;
    int t = threadIdx.x;
    float a0 = 0.f, a1 = 0.f, a2 = 0.f;
    int cnt = segCount[s];
    if (cnt > 0) {
        int q0 = segFirst[s];
        for (int i = 0; i < cnt; ++i) {
            const float* hr = hidden + (size_t)streamTok[q0 + i] * 768;
            a0 += hr[t]; a1 += hr[t + 256]; a2 += hr[t + 512];
        }
        float fc = (float)cnt;
        a0 /= fc; a1 /= fc; a2 /= fc;
    }
    size_t o = (size_t)(s - s0) * 768;
    means[o + t] = f2bf(a0); means[o + t + 256] = f2bf(a1); means[o + t + 512] = f2bf(a2);
}

// ---------- in-place row log_softmax over 1000 cols + constant fill (f32) ----------
__global__ __launch_bounds__(256) void softmax_rows(float* __restrict__ out,
                                                    const int* __restrict__ rowC)
{
    int v = blockIdx.x;
    int b = v >> 9, j = v & 511;
    int t = threadIdx.x;
    float* row = out + (size_t)v * 1000;
    if (j >= rowC[b]) {
        for (int e = t; e < 1000; e += 256) row[e] = -6.907755278982137f;  // log_softmax(0 row)
        return;
    }
    __shared__ float red[256];
    float x0 = row[t];
    float x1 = row[t + 256];
    float x2 = row[t + 512];
    bool has3 = (t + 768) < 1000;
    float x3 = has3 ? row[t + 768] : -1e30f;
    float mx = fmaxf(fmaxf(x0, x1), fmaxf(x2, x3));
    red[t] = mx; __syncthreads();
    for (int st = 128; st > 0; st >>= 1) { if (t < st) red[t] = fmaxf(red[t], red[t + st]); __syncthreads(); }
    float M = red[0]; __syncthreads();
    float sm = expf(x0 - M) + expf(x1 - M) + expf(x2 - M) + (has3 ? expf(x3 - M) : 0.f);
    red[t] = sm; __syncthreads();
    for (int st = 128; st > 0; st >>= 1) { if (t < st) red[t] += red[t + st]; __syncthreads(); }
    float ls = M + logf(red[0]);
    row[t]       = x0 - ls;
    row[t + 256] = x1 - ls;
    row[t + 512] = x2 - ls;
    if (has3) row[t + 768] = x3 - ls;
}

// ---------- launch ----------
extern "C" void kernel_launch(void* const* d_in, const int* in_sizes, int n_in,
                              void* d_out, int out_size, void* d_ws, size_t ws_size,
                              hipStream_t stream)
{
    (void)in_sizes; (void)n_in; (void)out_size; (void)ws_size;
    const int*   labels = (const int*)d_in[0];
    const float* hidden = (const float*)d_in[1];
    const float* ent    = (const float*)d_in[2];
    const float* w1     = (const float*)d_in[3];
    const float* b1     = (const float*)d_in[4];
    const float* w2     = (const float*)d_in[5];
    const float* b2     = (const float*)d_in[6];
    const float* wm     = (const float*)d_in[7];
    const float* wd     = (const float*)d_in[8];

    char* ws = (char*)d_ws;
    size_t off = 0;
    auto alloc = [&](size_t bytes) {
        void* p = ws + off;
        off = (off + bytes + 255) & ~(size_t)255;
        return p;
    };
    int* meta      = (int*)alloc(256);
    int* rowC      = (int*)alloc(256);
    int* rowStart  = (int*)alloc(256);
    int* predLab   = (int*)alloc(32768 * 4);
    int* streamTok = (int*)alloc(32768 * 4);
    int* cumArr    = (int*)alloc(32768 * 4);
    int* segCount  = (int*)alloc(32768 * 4);
    int* segFirst  = (int*)alloc(32768 * 4);
    int* mapArr    = (int*)alloc(32768 * 4);
    unsigned short* entB = (unsigned short*)alloc((size_t)1000 * 768 * 2);
    unsigned short* wdT  = (unsigned short*)alloc((size_t)300 * 768 * 2);
    unsigned short* pd   = (unsigned short*)alloc((size_t)1000 * 320 * 2);
    unsigned short* wmP  = (unsigned short*)alloc((size_t)768 * 320 * 2);
    unsigned short* W2t  = (unsigned short*)alloc((size_t)1000 * 768 * 2);
    float* part = (float*)alloc((size_t)12 * 98304 * 4);            // 4.7 MB
    unsigned short* meansChunk = (unsigned short*)alloc((size_t)4096 * 768 * 2);  // 6.3 MB

    float* out0 = (float*)d_out;
    float* out1 = out0 + 98304;
    float* out2 = out1 + (size_t)32768 * 1000;

    // ---- weight prep ----
    hipMemsetAsync(pd, 0, (size_t)1000 * 320 * 2, stream);
    hipMemsetAsync(wmP, 0, (size_t)768 * 320 * 2, stream);
    cast_bf16<<<3000, 256, 0, stream>>>(ent, entB, 768000);
    transpose_cast<<<dim3(10, 24), dim3(32, 8), 0, stream>>>(wd, wdT, 768, 300);
    cast_pad<<<900, 256, 0, stream>>>(wm, wmP, 768, 300, 320);
    // pd[e,p] = ent @ wd
    gemm_bt<<<dim3(8, 3), 256, 0, stream>>>(entB, wdT, pd, nullptr, nullptr,
                                            1000, 300, 768, 768, 768, 320, 0, 0);
    // W2t[e,h] = sum_p pd[e,p]*wm[h,p]
    gemm_bt<<<dim3(8, 6), 256, 0, stream>>>(pd, wmP, W2t, nullptr, nullptr,
                                            1000, 768, 320, 320, 320, 768, 0, 0);
    // fused h1 GEMM + partial bio logits (f32), then finalize
    h1_bio_gemm<<<dim3(512, 12), dim3(16, 16), 0, stream>>>(hidden, w1, b1, w2, part);
    bio_final<<<128, 256, 0, stream>>>(part, b2, out0, predLab);

    // ---- per label set: true labels then predicted labels ----
    for (int s = 0; s < 2; ++s) {
        const int* lab = (s == 0) ? labels : predLab;
        float* outS = (s == 0) ? out1 : out2;
        seg_init<<<128, 256, 0, stream>>>(segCount, segFirst, meta);
        seg_scan<<<1, 1024, 0, stream>>>(lab, streamTok, cumArr, meta);
        row_count<<<64, 256, 0, stream>>>(lab, rowC);
        seg_finalize<<<1, 64, 0, stream>>>(rowC, rowStart, meta);
        build_map<<<64, 256, 0, stream>>>(rowC, rowStart, mapArr);
        seg_assign<<<128, 256, 0, stream>>>(cumArr, segCount, segFirst, meta);
        // means + scattered dot-GEMM in 8 chunks of 4096 segments
        for (int c = 0; c < 8; ++c) {
            int s0 = c * 4096;
            seg_means<<<4096, 256, 0, stream>>>(hidden, streamTok, segCount, segFirst,
                                                meta, meansChunk, s0);
            gemm_bt<<<dim3(32, 8), 256, 0, stream>>>(meansChunk, W2t, outS, meta, mapArr,
                                                     0, 1000, 768, 768, 768, 1000, 2, s0);
        }
        softmax_rows<<<32768, 256, 0, stream>>>(outS, rowC);
    }
}

// Round 4
// 992.306 us; speedup vs baseline: 1.2332x; 1.2332x over previous
//
#include <hip/hip_runtime.h>
#include <stdint.h>

// ---------- helpers ----------
__device__ inline float bf2f(unsigned short u) { return __uint_as_float(((unsigned int)u) << 16); }
__device__ inline unsigned short f2bf(float f) {
    unsigned int x = __float_as_uint(f);
    unsigned int r = x + 0x7fffu + ((x >> 16) & 1u);   // RNE
    return (unsigned short)(r >> 16);
}

typedef __attribute__((ext_vector_type(8))) short bf16x8;
typedef __attribute__((ext_vector_type(4))) float f32x4;
typedef __attribute__((ext_vector_type(4))) int   v4i;

#define FLAG_CAP 8192
#define MARGIN 0.02

// ---------- MFMA GEMM: C[M,N] = A[M,K] * Bt[N,K]^T (A,Bt bf16) ----------
// mode 0: store bf16. mode 2: store f32 (with rowMap scatter).
__global__ __launch_bounds__(256) void gemm_bt(
    const unsigned short* __restrict__ A,
    const unsigned short* __restrict__ Bt,
    void* __restrict__ C,
    const int* __restrict__ Mdev,
    const int* __restrict__ rowMap,
    int M, int N, int K, int lda, int ldb, int ldc, int mode, int rowOff)
{
    if (Mdev) M = *Mdev;
    int mt = blockIdx.x, nt = blockIdx.y;
    if (rowOff + mt * 128 >= M) return;

    __shared__ __align__(16) unsigned short As[128 * 64];
    __shared__ __align__(16) unsigned short Bs[128 * 64];

    int tid  = threadIdx.x;
    int lane = tid & 63, wave = tid >> 6;
    int wRow = (wave >> 1) * 64, wCol = (wave & 1) * 64;
    int mBase = mt * 128, nBase = nt * 128;
    int lm = lane & 15, kg = lane >> 4;
    int sr = tid >> 3;
    int sc = (tid & 7) * 8;

    f32x4 acc[4][4] = {};

    for (int k0 = 0; k0 < K; k0 += 64) {
        __syncthreads();
#pragma unroll
        for (int i = 0; i < 4; ++i) {
            int r = sr + 32 * i;
            int gm = rowOff + mBase + r; if (gm > M - 1) gm = M - 1;
            *(v4i*)&As[r * 64 + sc] = *(const v4i*)&A[(size_t)(gm - rowOff) * lda + k0 + sc];
            int gn = nBase + r; if (gn > N - 1) gn = N - 1;
            *(v4i*)&Bs[r * 64 + sc] = *(const v4i*)&Bt[(size_t)gn * ldb + k0 + sc];
        }
        __syncthreads();
#pragma unroll
        for (int ks = 0; ks < 2; ++ks) {
            bf16x8 af[4], bfr[4];
#pragma unroll
            for (int i = 0; i < 4; ++i) {
                af[i]  = *(const bf16x8*)&As[(wRow + i * 16 + lm) * 64 + ks * 32 + kg * 8];
                bfr[i] = *(const bf16x8*)&Bs[(wCol + i * 16 + lm) * 64 + ks * 32 + kg * 8];
            }
#pragma unroll
            for (int mi = 0; mi < 4; ++mi)
#pragma unroll
                for (int ni = 0; ni < 4; ++ni)
                    acc[mi][ni] = __builtin_amdgcn_mfma_f32_16x16x32_bf16(
                        af[mi], bfr[ni], acc[mi][ni], 0, 0, 0);
        }
    }

    int rbase = (lane >> 4) * 4;
#pragma unroll
    for (int mi = 0; mi < 4; ++mi) {
#pragma unroll
        for (int r = 0; r < 4; ++r) {
            int m = rowOff + mBase + wRow + mi * 16 + rbase + r;
            if (m >= M) continue;
            size_t crow = rowMap ? (size_t)rowMap[m] * ldc : (size_t)(m - rowOff) * ldc;
#pragma unroll
            for (int ni = 0; ni < 4; ++ni) {
                int n = nBase + wCol + ni * 16 + lm;
                if (n >= N) continue;
                float v = acc[mi][ni][r];
                if (mode == 2) ((float*)C)[crow + n] = v;
                else           ((unsigned short*)C)[crow + n] = f2bf(v);
            }
        }
    }
}

// ---------- small prep kernels ----------
__global__ void cast_bf16(const float* __restrict__ in, unsigned short* __restrict__ out, int n)
{
    int i = blockIdx.x * 256 + threadIdx.x;
    if (i < n) out[i] = f2bf(in[i]);
}

__global__ void cast_pad(const float* __restrict__ in, unsigned short* __restrict__ out,
                         int rows, int cols, int ldo)
{
    int idx = blockIdx.x * 256 + threadIdx.x;
    if (idx < rows * cols) out[(size_t)(idx / cols) * ldo + (idx % cols)] = f2bf(in[idx]);
}

__global__ void transpose_cast(const float* __restrict__ in, unsigned short* __restrict__ out,
                               int R, int Ccols)
{
    __shared__ float tile[32][33];
    int c0 = blockIdx.x * 32, r0 = blockIdx.y * 32;
    int tx = threadIdx.x, ty = threadIdx.y;
#pragma unroll
    for (int i = 0; i < 4; ++i) {
        int r = r0 + ty + i * 8, c = c0 + tx;
        if (r < R && c < Ccols) tile[ty + i * 8][tx] = in[(size_t)r * Ccols + c];
    }
    __syncthreads();
#pragma unroll
    for (int i = 0; i < 4; ++i) {
        int orow = c0 + ty + i * 8;
        int ocol = r0 + tx;
        if (orow < Ccols && ocol < R) out[(size_t)orow * R + ocol] = f2bf(tile[tx][ty + i * 8]);
    }
}

// pack w1[768k][768n] into MFMA-B frag order: idx=(ks*48+ntile)*64+lane, 8 bf16 each
__global__ void pack_w1(const float* __restrict__ w1, unsigned short* __restrict__ Wp)
{
    int idx = blockIdx.x * 256 + threadIdx.x;
    if (idx >= 24 * 48 * 64) return;
    int lane = idx & 63;
    int ntile = (idx >> 6) % 48;
    int ks = idx / (48 * 64);
    int n = ntile * 16 + (lane & 15);
    int k0 = ks * 32 + (lane >> 4) * 8;
    unsigned short* dst = Wp + (size_t)idx * 8;
#pragma unroll
    for (int j = 0; j < 8; ++j) dst[j] = f2bf(w1[(size_t)(k0 + j) * 768 + n]);
}

// ---------- bf16-MFMA h1 + fused approx bio logits ----------
// block: 32 token rows; LDS A-strip; waves split n (192 each); atomicAdd part[t][3]
__global__ __launch_bounds__(256) void mfma_h1_logits(
    const float* __restrict__ A, const unsigned short* __restrict__ Wp,
    const float* __restrict__ b1, const float* __restrict__ w2,
    float* __restrict__ part)
{
    __shared__ __align__(16) unsigned short As[32][776];
    int tid = threadIdx.x, lane = tid & 63, wave = tid >> 6;
    int m0 = blockIdx.x * 32;
    {
        int row = tid >> 3, cseg = (tid & 7) * 96;
        const float* src = A + (size_t)(m0 + row) * 768 + cseg;
        unsigned short* dst = &As[row][cseg];
#pragma unroll
        for (int i = 0; i < 96; i += 4) {
            float4 v = *(const float4*)&src[i];
            dst[i+0] = f2bf(v.x); dst[i+1] = f2bf(v.y);
            dst[i+2] = f2bf(v.z); dst[i+3] = f2bf(v.w);
        }
    }
    __syncthreads();
    int lm = lane & 15, kg = lane >> 4;

    f32x4 acc[12][2];
#pragma unroll
    for (int i = 0; i < 12; ++i) { acc[i][0] = (f32x4){0,0,0,0}; acc[i][1] = (f32x4){0,0,0,0}; }

    for (int ks = 0; ks < 24; ++ks) {
        bf16x8 af0 = *(const bf16x8*)&As[lm][ks * 32 + kg * 8];
        bf16x8 af1 = *(const bf16x8*)&As[16 + lm][ks * 32 + kg * 8];
        const unsigned short* wpk = Wp + (((size_t)ks * 48 + wave * 12) * 64 + lane) * 8;
#pragma unroll
        for (int nt = 0; nt < 12; ++nt) {
            bf16x8 bf = *(const bf16x8*)(wpk + (size_t)nt * 512);
            acc[nt][0] = __builtin_amdgcn_mfma_f32_16x16x32_bf16(af0, bf, acc[nt][0], 0, 0, 0);
            acc[nt][1] = __builtin_amdgcn_mfma_f32_16x16x32_bf16(af1, bf, acc[nt][1], 0, 0, 0);
        }
    }

    // epilogue: partial logits over this wave's 192 n-columns
    float p[2][4][3] = {};
    int nw0 = wave * 192;
#pragma unroll
    for (int nt = 0; nt < 12; ++nt) {
        int n = nw0 + nt * 16 + lm;
        float b1v = b1[n];
        float w0 = w2[n * 3 + 0], w1v = w2[n * 3 + 1], w2v = w2[n * 3 + 2];
#pragma unroll
        for (int mt = 0; mt < 2; ++mt)
#pragma unroll
            for (int r = 0; r < 4; ++r) {
                float v = acc[nt][mt][r] + b1v;
                v = fmaxf(v, 0.f);
                p[mt][r][0] += v * w0; p[mt][r][1] += v * w1v; p[mt][r][2] += v * w2v;
            }
    }
#pragma unroll
    for (int mt = 0; mt < 2; ++mt)
#pragma unroll
        for (int r = 0; r < 4; ++r)
#pragma unroll
            for (int c = 0; c < 3; ++c) {
                float s = p[mt][r][c];
                s += __shfl_down(s, 8); s += __shfl_down(s, 4);
                s += __shfl_down(s, 2); s += __shfl_down(s, 1);
                p[mt][r][c] = s;
            }
    if (lm == 0) {
        int quad = kg;
#pragma unroll
        for (int mt = 0; mt < 2; ++mt)
#pragma unroll
            for (int r = 0; r < 4; ++r) {
                int row = m0 + mt * 16 + quad * 4 + r;
#pragma unroll
                for (int c = 0; c < 3; ++c)
                    atomicAdd(&part[(size_t)row * 3 + c], p[mt][r][c]);
            }
    }
}

// ---------- finalize approx logits, flag marginal tokens ----------
__global__ void bio_final2(const float* __restrict__ part, const float* __restrict__ b2,
                           float* __restrict__ out0, int* __restrict__ predLab,
                           int* __restrict__ flagCnt, int* __restrict__ flagList)
{
    int t = blockIdx.x * 256 + threadIdx.x;
    double a[3];
#pragma unroll
    for (int c = 0; c < 3; ++c) a[c] = (double)part[(size_t)t * 3 + c] + (double)b2[c];
    double mx = a[0]; if (a[1] > mx) mx = a[1]; if (a[2] > mx) mx = a[2];
    double ls = mx + log(exp(a[0] - mx) + exp(a[1] - mx) + exp(a[2] - mx));
    out0[t * 3 + 0] = (float)(a[0] - ls);
    out0[t * 3 + 1] = (float)(a[1] - ls);
    out0[t * 3 + 2] = (float)(a[2] - ls);
    int pbest = 0; double bv = a[0];
    if (a[1] > bv) { bv = a[1]; pbest = 1; }
    if (a[2] > bv) { bv = a[2]; pbest = 2; }
    predLab[t] = pbest;
    // top-2 gap
    double second = -1e300;
#pragma unroll
    for (int c = 0; c < 3; ++c) if (c != pbest && a[c] > second) second = a[c];
    if (bv - second < MARGIN) {
        int i = atomicAdd(flagCnt, 1);
        if (i < FLAG_CAP) flagList[i] = t;
    }
}

// ---------- gather flagged token rows into compact Af ----------
__global__ void gather_rows(const float* __restrict__ A, const int* __restrict__ flagList,
                            const int* __restrict__ flagCnt, float* __restrict__ Af)
{
    int b = blockIdx.x;
    int cnt = *flagCnt; if (cnt > FLAG_CAP) cnt = FLAG_CAP;
    if (b >= cnt) return;
    const float* src = A + (size_t)flagList[b] * 768;
    float* dst = Af + (size_t)b * 768;
    int t = threadIdx.x;
    dst[t] = src[t]; dst[t + 256] = src[t + 256]; dst[t + 512] = src[t + 512];
}

// ---------- exact f32 h1+partial-logit GEMM on flagged rows (round-3 kernel) ----------
__global__ __launch_bounds__(256) void h1_bio_gemm(
    const float* __restrict__ A, const float* __restrict__ W,
    const float* __restrict__ b1, const float* __restrict__ w2,
    float* __restrict__ part, const int* __restrict__ Mdev, int partStride)
{
    int M = *Mdev; if (M > FLAG_CAP) M = FLAG_CAP;
    if (M <= 0) return;
    int m0 = blockIdx.x * 64, n0 = blockIdx.y * 64;
    if (m0 >= M) return;
    __shared__ float AsT[16][64];
    __shared__ float Ws[16][64];
    int tx = threadIdx.x, ty = threadIdx.y;
    int tid = ty * 16 + tx;
    float acc[4][4] = {};

    for (int k0 = 0; k0 < 768; k0 += 16) {
        __syncthreads();
        {
            int row = tid >> 2, seg = (tid & 3) * 4;
            int gm = m0 + row; if (gm > M - 1) gm = M - 1;
            float4 v = *(const float4*)&A[(size_t)gm * 768 + k0 + seg];
            AsT[seg + 0][row] = v.x; AsT[seg + 1][row] = v.y;
            AsT[seg + 2][row] = v.z; AsT[seg + 3][row] = v.w;
        }
        {
            int row = tid >> 4, seg = (tid & 15) * 4;
            *(float4*)&Ws[row][seg] = *(const float4*)&W[(size_t)(k0 + row) * 768 + n0 + seg];
        }
        __syncthreads();
#pragma unroll
        for (int kk = 0; kk < 16; ++kk) {
            float4 av = *(const float4*)&AsT[kk][ty * 4];
            float4 bv = *(const float4*)&Ws[kk][tx * 4];
            float a[4] = {av.x, av.y, av.z, av.w};
            float b[4] = {bv.x, bv.y, bv.z, bv.w};
#pragma unroll
            for (int i = 0; i < 4; ++i)
#pragma unroll
                for (int j = 0; j < 4; ++j)
                    acc[i][j] += a[i] * b[j];
        }
    }

    float b1v[4], w2l[4][3];
#pragma unroll
    for (int j = 0; j < 4; ++j) {
        int n = n0 + tx * 4 + j;
        b1v[j] = b1[n];
#pragma unroll
        for (int c = 0; c < 3; ++c) w2l[j][c] = w2[n * 3 + c];
    }
    float p[4][3] = {};
#pragma unroll
    for (int i = 0; i < 4; ++i)
#pragma unroll
        for (int j = 0; j < 4; ++j) {
            float v = acc[i][j] + b1v[j];
            v = fmaxf(v, 0.f);
#pragma unroll
            for (int c = 0; c < 3; ++c) p[i][c] += v * w2l[j][c];
        }
#pragma unroll
    for (int i = 0; i < 4; ++i)
#pragma unroll
        for (int c = 0; c < 3; ++c) {
            float s = p[i][c];
            s += __shfl_down(s, 8); s += __shfl_down(s, 4);
            s += __shfl_down(s, 2); s += __shfl_down(s, 1);
            p[i][c] = s;
        }
    if (tx == 0) {
#pragma unroll
        for (int i = 0; i < 4; ++i) {
            int t = m0 + ty * 4 + i;
            if (t >= M) continue;
#pragma unroll
            for (int c = 0; c < 3; ++c)
                part[(size_t)blockIdx.y * partStride + (size_t)t * 3 + c] = p[i][c];
        }
    }
}

// ---------- exact argmax for flagged tokens ----------
__global__ void bio_final_fix(const float* __restrict__ partF, const float* __restrict__ b2,
                              const int* __restrict__ flagList, const int* __restrict__ flagCnt,
                              int* __restrict__ predLab, int partStride)
{
    int i = blockIdx.x * 256 + threadIdx.x;
    int cnt = *flagCnt; if (cnt > FLAG_CAP) cnt = FLAG_CAP;
    if (i >= cnt) return;
    double a[3] = {(double)b2[0], (double)b2[1], (double)b2[2]};
#pragma unroll
    for (int blk = 0; blk < 12; ++blk)
#pragma unroll
        for (int c = 0; c < 3; ++c)
            a[c] += (double)partF[(size_t)blk * partStride + (size_t)i * 3 + c];
    int pbest = 0; double bv = a[0];
    if (a[1] > bv) { bv = a[1]; pbest = 1; }
    if (a[2] > bv) { bv = a[2]; pbest = 2; }
    predLab[flagList[i]] = pbest;
}

// ---------- merged segmentation prep (single block) ----------
// meta: [0]=numB [1]=K [2]=idx0
__global__ __launch_bounds__(1024) void seg_prep(
    const int* __restrict__ lab, int* __restrict__ streamTok, int* __restrict__ cumArr,
    int* __restrict__ meta, int* __restrict__ segCount, int* __restrict__ segFirst,
    int* __restrict__ rowC, int* __restrict__ rowStart, int* __restrict__ mapArr)
{
    __shared__ int sM[1024], sB[1024];
    __shared__ int sRowC[64], sRowStart[64];
    __shared__ int sIdx0;
    int t = threadIdx.x;
    for (int i = t; i < 32768; i += 1024) { segCount[i] = 0; segFirst[i] = 0x7fffffff; }
    if (t == 0) sIdx0 = 0x7fffffff;
    int base = t * 32;
    int mc = 0, bc = 0;
    for (int i = 0; i < 32; ++i) { int v = lab[base + i]; mc += (v != 0); bc += (v == 1); }
    sM[t] = mc; sB[t] = bc; __syncthreads();
    for (int off = 1; off < 1024; off <<= 1) {
        int vm = 0, vb = 0;
        if (t >= off) { vm = sM[t - off]; vb = sB[t - off]; }
        __syncthreads();
        sM[t] += vm; sB[t] += vb;
        __syncthreads();
    }
    int mBase = sM[t] - mc, bBase = sB[t] - bc;
    int mRun = 0, bRun = 0;
    for (int i = 0; i < 32; ++i) {
        int v = lab[base + i];
        if (v != 0) {
            int q = mBase + mRun;
            streamTok[q] = base + i;
            int isB = (v == 1);
            cumArr[q] = bBase + bRun + isB;
            if (isB && (bBase + bRun) == 0) sIdx0 = q;   // unique thread
            mRun += 1; bRun += isB;
        }
    }
    if ((t & 15) == 0) {
        int b = t >> 4;
        sRowStart[b] = bBase;            // B's before row b
    }
    __syncthreads();
    if ((t & 15) == 0) {
        int b = t >> 4;
        int endIncl = sB[t + 15];
        sRowC[b] = endIncl - sRowStart[b];
        rowStart[b] = sRowStart[b];
        rowC[b] = sRowC[b];
    }
    if (t == 1023) { meta[0] = sB[1023]; meta[1] = sM[1023]; }
    if (t == 0) meta[2] = (sIdx0 == 0x7fffffff) ? 0 : sIdx0;
    __syncthreads();
    for (int idx = t; idx < 32768; idx += 1024) {
        int b = idx >> 9, j = idx & 511;
        if (j < sRowC[b]) mapArr[sRowStart[b] + j] = idx;
    }
}

__global__ void seg_assign(const int* __restrict__ cumArr, int* __restrict__ segCount,
                           int* __restrict__ segFirst, const int* __restrict__ meta)
{
    int q = blockIdx.x * 256 + threadIdx.x;
    int K = meta[1];
    if (q >= K) return;
    int numB = meta[0], idx0 = meta[2];
    int qq = q + idx0;
    int cumv = (qq < K) ? cumArr[qq] : numB;
    int seg = cumv - 1;
    if (seg >= 0) {
        atomicAdd(&segCount[seg], 1);
        atomicMin(&segFirst[seg], q);
    }
}

// means for segments [s0, s0+8192) -> bf16 chunk rows [0,8192)
__global__ __launch_bounds__(256) void seg_means(
    const float* __restrict__ hidden, const int* __restrict__ streamTok,
    const int* __restrict__ segCount, const int* __restrict__ segFirst,
    const int* __restrict__ meta, unsigned short* __restrict__ means, int s0)
{
    int s = s0 + blockIdx.x;
    if (s >= meta[0]) return;
    int t = threadIdx.x;
    float a0 = 0.f, a1 = 0.f, a2 = 0.f;
    int cnt = segCount[s];
    if (cnt > 0) {
        int q0 = segFirst[s];
        for (int i = 0; i < cnt; ++i) {
            const float* hr = hidden + (size_t)streamTok[q0 + i] * 768;
            a0 += hr[t]; a1 += hr[t + 256]; a2 += hr[t + 512];
        }
        float fc = (float)cnt;
        a0 /= fc; a1 /= fc; a2 /= fc;
    }
    size_t o = (size_t)(s - s0) * 768;
    means[o + t] = f2bf(a0); means[o + t + 256] = f2bf(a1); means[o + t + 512] = f2bf(a2);
}

// ---------- in-place row log_softmax over 1000 cols + constant fill ----------
__global__ __launch_bounds__(256) void softmax_rows(float* __restrict__ out,
                                                    const int* __restrict__ rowC)
{
    int v = blockIdx.x;
    int b = v >> 9, j = v & 511;
    int t = threadIdx.x;
    float* row = out + (size_t)v * 1000;
    if (j >= rowC[b]) {
        for (int e = t; e < 1000; e += 256) row[e] = -6.907755278982137f;
        return;
    }
    __shared__ float red[256];
    float x0 = row[t];
    float x1 = row[t + 256];
    float x2 = row[t + 512];
    bool has3 = (t + 768) < 1000;
    float x3 = has3 ? row[t + 768] : -1e30f;
    float mx = fmaxf(fmaxf(x0, x1), fmaxf(x2, x3));
    red[t] = mx; __syncthreads();
    for (int st = 128; st > 0; st >>= 1) { if (t < st) red[t] = fmaxf(red[t], red[t + st]); __syncthreads(); }
    float M = red[0]; __syncthreads();
    float sm = expf(x0 - M) + expf(x1 - M) + expf(x2 - M) + (has3 ? expf(x3 - M) : 0.f);
    red[t] = sm; __syncthreads();
    for (int st = 128; st > 0; st >>= 1) { if (t < st) red[t] += red[t + st]; __syncthreads(); }
    float ls = M + logf(red[0]);
    row[t]       = x0 - ls;
    row[t + 256] = x1 - ls;
    row[t + 512] = x2 - ls;
    if (has3) row[t + 768] = x3 - ls;
}

// ---------- launch ----------
extern "C" void kernel_launch(void* const* d_in, const int* in_sizes, int n_in,
                              void* d_out, int out_size, void* d_ws, size_t ws_size,
                              hipStream_t stream)
{
    (void)in_sizes; (void)n_in; (void)out_size; (void)ws_size;
    const int*   labels = (const int*)d_in[0];
    const float* hidden = (const float*)d_in[1];
    const float* ent    = (const float*)d_in[2];
    const float* w1     = (const float*)d_in[3];
    const float* b1     = (const float*)d_in[4];
    const float* w2     = (const float*)d_in[5];
    const float* b2     = (const float*)d_in[6];
    const float* wm     = (const float*)d_in[7];
    const float* wd     = (const float*)d_in[8];

    char* ws = (char*)d_ws;
    size_t off = 0;
    auto alloc = [&](size_t bytes) {
        void* p = ws + off;
        off = (off + bytes + 255) & ~(size_t)255;
        return p;
    };
    int* meta      = (int*)alloc(256);
    int* rowC      = (int*)alloc(256);
    int* rowStart  = (int*)alloc(256);
    int* flagCnt   = (int*)alloc(256);
    int* predLab   = (int*)alloc(32768 * 4);
    int* streamTok = (int*)alloc(32768 * 4);
    int* cumArr    = (int*)alloc(32768 * 4);
    int* segCount  = (int*)alloc(32768 * 4);
    int* segFirst  = (int*)alloc(32768 * 4);
    int* mapArr    = (int*)alloc(32768 * 4);
    int* flagList  = (int*)alloc(FLAG_CAP * 4);
    unsigned short* entB = (unsigned short*)alloc((size_t)1000 * 768 * 2);
    unsigned short* wdT  = (unsigned short*)alloc((size_t)300 * 768 * 2);
    unsigned short* pd   = (unsigned short*)alloc((size_t)1000 * 320 * 2);
    unsigned short* wmP  = (unsigned short*)alloc((size_t)768 * 320 * 2);
    unsigned short* W2t  = (unsigned short*)alloc((size_t)1000 * 768 * 2);
    unsigned short* Wp   = (unsigned short*)alloc((size_t)24 * 48 * 64 * 8 * 2);  // 1.18 MB
    float* part  = (float*)alloc((size_t)32768 * 3 * 4);                 // 393 KB
    float* partF = (float*)alloc((size_t)12 * FLAG_CAP * 3 * 4);         // 1.18 MB
    float* Af    = (float*)alloc((size_t)FLAG_CAP * 768 * 4);            // 25.2 MB
    unsigned short* meansChunk = (unsigned short*)alloc((size_t)8192 * 768 * 2); // 12.6 MB

    float* out0 = (float*)d_out;
    float* out1 = out0 + 98304;
    float* out2 = out1 + (size_t)32768 * 1000;

    // ---- weight prep ----
    hipMemsetAsync(pd, 0, (size_t)1000 * 320 * 2, stream);
    hipMemsetAsync(wmP, 0, (size_t)768 * 320 * 2, stream);
    hipMemsetAsync(part, 0, (size_t)32768 * 3 * 4, stream);
    hipMemsetAsync(flagCnt, 0, 4, stream);
    cast_bf16<<<3000, 256, 0, stream>>>(ent, entB, 768000);
    transpose_cast<<<dim3(10, 24), dim3(32, 8), 0, stream>>>(wd, wdT, 768, 300);
    cast_pad<<<900, 256, 0, stream>>>(wm, wmP, 768, 300, 320);
    pack_w1<<<288, 256, 0, stream>>>(w1, Wp);
    gemm_bt<<<dim3(8, 3), 256, 0, stream>>>(entB, wdT, pd, nullptr, nullptr,
                                            1000, 300, 768, 768, 768, 320, 0, 0);
    gemm_bt<<<dim3(8, 6), 256, 0, stream>>>(pd, wmP, W2t, nullptr, nullptr,
                                            1000, 768, 320, 320, 320, 768, 0, 0);

    // ---- h1 path: bf16 MFMA approx + exact rescue of marginal tokens ----
    mfma_h1_logits<<<1024, 256, 0, stream>>>(hidden, Wp, b1, w2, part);
    bio_final2<<<128, 256, 0, stream>>>(part, b2, out0, predLab, flagCnt, flagList);
    gather_rows<<<FLAG_CAP, 256, 0, stream>>>(hidden, flagList, flagCnt, Af);
    h1_bio_gemm<<<dim3(FLAG_CAP / 64, 12), dim3(16, 16), 0, stream>>>(
        Af, w1, b1, w2, partF, flagCnt, FLAG_CAP * 3);
    bio_final_fix<<<FLAG_CAP / 256, 256, 0, stream>>>(partF, b2, flagList, flagCnt,
                                                      predLab, FLAG_CAP * 3);

    // ---- per label set: true labels then predicted labels ----
    for (int s = 0; s < 2; ++s) {
        const int* lab = (s == 0) ? labels : predLab;
        float* outS = (s == 0) ? out1 : out2;
        seg_prep<<<1, 1024, 0, stream>>>(lab, streamTok, cumArr, meta, segCount, segFirst,
                                         rowC, rowStart, mapArr);
        seg_assign<<<128, 256, 0, stream>>>(cumArr, segCount, segFirst, meta);
        for (int c = 0; c < 4; ++c) {
            int s0 = c * 8192;
            seg_means<<<8192, 256, 0, stream>>>(hidden, streamTok, segCount, segFirst,
                                                meta, meansChunk, s0);
            gemm_bt<<<dim3(64, 8), 256, 0, stream>>>(meansChunk, W2t, outS, meta, mapArr,
                                                     0, 1000, 768, 768, 768, 1000, 2, s0);
        }
        softmax_rows<<<32768, 256, 0, stream>>>(outS, rowC);
    }
}

// Round 5
// 934.317 us; speedup vs baseline: 1.3097x; 1.0621x over previous
//
#include <hip/hip_runtime.h>
#include <stdint.h>

// ---------- helpers ----------
__device__ inline float bf2f(unsigned short u) { return __uint_as_float(((unsigned int)u) << 16); }
__device__ inline unsigned short f2bf(float f) {
    unsigned int x = __float_as_uint(f);
    unsigned int r = x + 0x7fffu + ((x >> 16) & 1u);   // RNE
    return (unsigned short)(r >> 16);
}

typedef __attribute__((ext_vector_type(8))) short bf16x8;
typedef __attribute__((ext_vector_type(4))) float f32x4;
typedef __attribute__((ext_vector_type(4))) int   v4i;
typedef __attribute__((ext_vector_type(4))) unsigned short u16x4;

#define FLAG_CAP 8192
#define MARGIN 0.02

// ---------- MFMA GEMM: C[M,N] = A[M,K] * Bt[N,K]^T (A,Bt bf16) ----------
// grid: x = n-tile (fast, for A-tile L2 reuse), y = m-tile.
// mode 0: store bf16. mode 2: store f32 with rowMap scatter.
// mode 3: fused bio epilogue: atomicAdd fpart[row][c] += sum_n relu(v+fb1[n])*fw2[n][c]
__global__ __launch_bounds__(256) void gemm_bt(
    const unsigned short* __restrict__ A,
    const unsigned short* __restrict__ Bt,
    void* __restrict__ C,
    const int* __restrict__ Mdev,
    const int* __restrict__ rowMap,
    const float* __restrict__ fb1,
    const float* __restrict__ fw2,
    float* __restrict__ fpart,
    int M, int N, int K, int lda, int ldb, int ldc, int mode, int rowOff)
{
    if (Mdev) M = *Mdev;
    int nt = blockIdx.x, mt = blockIdx.y;
    if (rowOff + mt * 128 >= M) return;

    __shared__ __align__(16) unsigned short As[128 * 64];
    __shared__ __align__(16) unsigned short Bs[128 * 64];

    int tid  = threadIdx.x;
    int lane = tid & 63, wave = tid >> 6;
    int wRow = (wave >> 1) * 64, wCol = (wave & 1) * 64;
    int mBase = mt * 128, nBase = nt * 128;
    int lm = lane & 15, kg = lane >> 4;
    int sr = tid >> 3;
    int sc = (tid & 7) * 8;

    f32x4 acc[4][4] = {};

    for (int k0 = 0; k0 < K; k0 += 64) {
        __syncthreads();
#pragma unroll
        for (int i = 0; i < 4; ++i) {
            int r = sr + 32 * i;
            int gm = rowOff + mBase + r; if (gm > M - 1) gm = M - 1;
            *(v4i*)&As[r * 64 + sc] = *(const v4i*)&A[(size_t)(gm - rowOff) * lda + k0 + sc];
            int gn = nBase + r; if (gn > N - 1) gn = N - 1;
            *(v4i*)&Bs[r * 64 + sc] = *(const v4i*)&Bt[(size_t)gn * ldb + k0 + sc];
        }
        __syncthreads();
#pragma unroll
        for (int ks = 0; ks < 2; ++ks) {
            bf16x8 af[4], bfr[4];
#pragma unroll
            for (int i = 0; i < 4; ++i) {
                af[i]  = *(const bf16x8*)&As[(wRow + i * 16 + lm) * 64 + ks * 32 + kg * 8];
                bfr[i] = *(const bf16x8*)&Bs[(wCol + i * 16 + lm) * 64 + ks * 32 + kg * 8];
            }
#pragma unroll
            for (int mi = 0; mi < 4; ++mi)
#pragma unroll
                for (int ni = 0; ni < 4; ++ni)
                    acc[mi][ni] = __builtin_amdgcn_mfma_f32_16x16x32_bf16(
                        af[mi], bfr[ni], acc[mi][ni], 0, 0, 0);
        }
    }

    int rbase = (lane >> 4) * 4;

    if (mode == 3) {
        // per-ni column constants (n has no bounds issue: N multiple of 128 here)
        float b1v[4], w2l[4][3];
#pragma unroll
        for (int ni = 0; ni < 4; ++ni) {
            int n = nBase + wCol + ni * 16 + lm;
            b1v[ni] = fb1[n];
#pragma unroll
            for (int c = 0; c < 3; ++c) w2l[ni][c] = fw2[n * 3 + c];
        }
#pragma unroll
        for (int mi = 0; mi < 4; ++mi) {
            float p[4][3] = {};
#pragma unroll
            for (int ni = 0; ni < 4; ++ni)
#pragma unroll
                for (int r = 0; r < 4; ++r) {
                    float v = acc[mi][ni][r] + b1v[ni];
                    v = fmaxf(v, 0.f);
                    p[r][0] += v * w2l[ni][0];
                    p[r][1] += v * w2l[ni][1];
                    p[r][2] += v * w2l[ni][2];
                }
#pragma unroll
            for (int r = 0; r < 4; ++r)
#pragma unroll
                for (int c = 0; c < 3; ++c) {
                    float s = p[r][c];
                    s += __shfl_down(s, 8); s += __shfl_down(s, 4);
                    s += __shfl_down(s, 2); s += __shfl_down(s, 1);
                    p[r][c] = s;
                }
            if (lm == 0) {
#pragma unroll
                for (int r = 0; r < 4; ++r) {
                    int row = mBase + wRow + mi * 16 + rbase + r;
#pragma unroll
                    for (int c = 0; c < 3; ++c)
                        atomicAdd(&fpart[(size_t)row * 3 + c], p[r][c]);
                }
            }
        }
        return;
    }

#pragma unroll
    for (int mi = 0; mi < 4; ++mi) {
#pragma unroll
        for (int r = 0; r < 4; ++r) {
            int m = rowOff + mBase + wRow + mi * 16 + rbase + r;
            if (m >= M) continue;
            size_t crow = rowMap ? (size_t)rowMap[m] * ldc : (size_t)(m - rowOff) * ldc;
#pragma unroll
            for (int ni = 0; ni < 4; ++ni) {
                int n = nBase + wCol + ni * 16 + lm;
                if (n >= N) continue;
                float v = acc[mi][ni][r];
                if (mode == 2) ((float*)C)[crow + n] = v;
                else           ((unsigned short*)C)[crow + n] = f2bf(v);
            }
        }
    }
}

// ---------- small prep kernels ----------
__global__ void cast_bf16_v4(const float* __restrict__ in, unsigned short* __restrict__ out,
                             int n4)
{
    int i = blockIdx.x * 256 + threadIdx.x;
    if (i < n4) {
        float4 v = ((const float4*)in)[i];
        u16x4 o = { f2bf(v.x), f2bf(v.y), f2bf(v.z), f2bf(v.w) };
        ((u16x4*)out)[i] = o;
    }
}

__global__ void cast_pad(const float* __restrict__ in, unsigned short* __restrict__ out,
                         int rows, int cols, int ldo)
{
    int idx = blockIdx.x * 256 + threadIdx.x;
    if (idx < rows * cols) out[(size_t)(idx / cols) * ldo + (idx % cols)] = f2bf(in[idx]);
}

__global__ void transpose_cast(const float* __restrict__ in, unsigned short* __restrict__ out,
                               int R, int Ccols)
{
    __shared__ float tile[32][33];
    int c0 = blockIdx.x * 32, r0 = blockIdx.y * 32;
    int tx = threadIdx.x, ty = threadIdx.y;
#pragma unroll
    for (int i = 0; i < 4; ++i) {
        int r = r0 + ty + i * 8, c = c0 + tx;
        if (r < R && c < Ccols) tile[ty + i * 8][tx] = in[(size_t)r * Ccols + c];
    }
    __syncthreads();
#pragma unroll
    for (int i = 0; i < 4; ++i) {
        int orow = c0 + ty + i * 8;
        int ocol = r0 + tx;
        if (orow < Ccols && ocol < R) out[(size_t)orow * R + ocol] = f2bf(tile[tx][ty + i * 8]);
    }
}

// ---------- finalize approx logits, flag marginal tokens ----------
__global__ void bio_final2(const float* __restrict__ part, const float* __restrict__ b2,
                           float* __restrict__ out0, int* __restrict__ predLab,
                           int* __restrict__ flagCnt, int* __restrict__ flagList)
{
    int t = blockIdx.x * 256 + threadIdx.x;
    double a[3];
#pragma unroll
    for (int c = 0; c < 3; ++c) a[c] = (double)part[(size_t)t * 3 + c] + (double)b2[c];
    double mx = a[0]; if (a[1] > mx) mx = a[1]; if (a[2] > mx) mx = a[2];
    double ls = mx + log(exp(a[0] - mx) + exp(a[1] - mx) + exp(a[2] - mx));
    out0[t * 3 + 0] = (float)(a[0] - ls);
    out0[t * 3 + 1] = (float)(a[1] - ls);
    out0[t * 3 + 2] = (float)(a[2] - ls);
    int pbest = 0; double bv = a[0];
    if (a[1] > bv) { bv = a[1]; pbest = 1; }
    if (a[2] > bv) { bv = a[2]; pbest = 2; }
    predLab[t] = pbest;
    double second = -1e300;
#pragma unroll
    for (int c = 0; c < 3; ++c) if (c != pbest && a[c] > second) second = a[c];
    if (bv - second < MARGIN) {
        int i = atomicAdd(flagCnt, 1);
        if (i < FLAG_CAP) flagList[i] = t;
    }
}

// ---------- gather flagged token rows (f32, exact) ----------
__global__ void gather_rows(const float* __restrict__ A, const int* __restrict__ flagList,
                            const int* __restrict__ flagCnt, float* __restrict__ Af)
{
    int b = blockIdx.x;
    int cnt = *flagCnt; if (cnt > FLAG_CAP) cnt = FLAG_CAP;
    if (b >= cnt) return;
    const float* src = A + (size_t)flagList[b] * 768;
    float* dst = Af + (size_t)b * 768;
    int t = threadIdx.x;
    dst[t] = src[t]; dst[t + 256] = src[t + 256]; dst[t + 512] = src[t + 512];
}

// ---------- exact f32 h1+partial-logit GEMM on flagged rows ----------
__global__ __launch_bounds__(256) void h1_bio_gemm(
    const float* __restrict__ A, const float* __restrict__ W,
    const float* __restrict__ b1, const float* __restrict__ w2,
    float* __restrict__ part, const int* __restrict__ Mdev, int partStride)
{
    int M = *Mdev; if (M > FLAG_CAP) M = FLAG_CAP;
    if (M <= 0) return;
    int m0 = blockIdx.x * 64, n0 = blockIdx.y * 64;
    if (m0 >= M) return;
    __shared__ float AsT[16][64];
    __shared__ float Ws[16][64];
    int tx = threadIdx.x, ty = threadIdx.y;
    int tid = ty * 16 + tx;
    float acc[4][4] = {};

    for (int k0 = 0; k0 < 768; k0 += 16) {
        __syncthreads();
        {
            int row = tid >> 2, seg = (tid & 3) * 4;
            int gm = m0 + row; if (gm > M - 1) gm = M - 1;
            float4 v = *(const float4*)&A[(size_t)gm * 768 + k0 + seg];
            AsT[seg + 0][row] = v.x; AsT[seg + 1][row] = v.y;
            AsT[seg + 2][row] = v.z; AsT[seg + 3][row] = v.w;
        }
        {
            int row = tid >> 4, seg = (tid & 15) * 4;
            *(float4*)&Ws[row][seg] = *(const float4*)&W[(size_t)(k0 + row) * 768 + n0 + seg];
        }
        __syncthreads();
#pragma unroll
        for (int kk = 0; kk < 16; ++kk) {
            float4 av = *(const float4*)&AsT[kk][ty * 4];
            float4 bv = *(const float4*)&Ws[kk][tx * 4];
            float a[4] = {av.x, av.y, av.z, av.w};
            float b[4] = {bv.x, bv.y, bv.z, bv.w};
#pragma unroll
            for (int i = 0; i < 4; ++i)
#pragma unroll
                for (int j = 0; j < 4; ++j)
                    acc[i][j] += a[i] * b[j];
        }
    }

    float b1v[4], w2l[4][3];
#pragma unroll
    for (int j = 0; j < 4; ++j) {
        int n = n0 + tx * 4 + j;
        b1v[j] = b1[n];
#pragma unroll
        for (int c = 0; c < 3; ++c) w2l[j][c] = w2[n * 3 + c];
    }
    float p[4][3] = {};
#pragma unroll
    for (int i = 0; i < 4; ++i)
#pragma unroll
        for (int j = 0; j < 4; ++j) {
            float v = acc[i][j] + b1v[j];
            v = fmaxf(v, 0.f);
#pragma unroll
            for (int c = 0; c < 3; ++c) p[i][c] += v * w2l[j][c];
        }
#pragma unroll
    for (int i = 0; i < 4; ++i)
#pragma unroll
        for (int c = 0; c < 3; ++c) {
            float s = p[i][c];
            s += __shfl_down(s, 8); s += __shfl_down(s, 4);
            s += __shfl_down(s, 2); s += __shfl_down(s, 1);
            p[i][c] = s;
        }
    if (tx == 0) {
#pragma unroll
        for (int i = 0; i < 4; ++i) {
            int t = m0 + ty * 4 + i;
            if (t >= M) continue;
#pragma unroll
            for (int c = 0; c < 3; ++c)
                part[(size_t)blockIdx.y * partStride + (size_t)t * 3 + c] = p[i][c];
        }
    }
}

// ---------- exact argmax for flagged tokens ----------
__global__ void bio_final_fix(const float* __restrict__ partF, const float* __restrict__ b2,
                              const int* __restrict__ flagList, const int* __restrict__ flagCnt,
                              int* __restrict__ predLab, int partStride)
{
    int i = blockIdx.x * 256 + threadIdx.x;
    int cnt = *flagCnt; if (cnt > FLAG_CAP) cnt = FLAG_CAP;
    if (i >= cnt) return;
    double a[3] = {(double)b2[0], (double)b2[1], (double)b2[2]};
#pragma unroll
    for (int blk = 0; blk < 12; ++blk)
#pragma unroll
        for (int c = 0; c < 3; ++c)
            a[c] += (double)partF[(size_t)blk * partStride + (size_t)i * 3 + c];
    int pbest = 0; double bv = a[0];
    if (a[1] > bv) { bv = a[1]; pbest = 1; }
    if (a[2] > bv) { bv = a[2]; pbest = 2; }
    predLab[flagList[i]] = pbest;
}

// ---------- parallel per-set init ----------
__global__ void seg_init(int* segCount, int* segFirst)
{
    int i = blockIdx.x * 256 + threadIdx.x;
    segCount[i] = 0;
    segFirst[i] = 0x7fffffff;
}

// ---------- merged segmentation prep (single block) ----------
// meta: [0]=numB [1]=K [2]=idx0
__global__ __launch_bounds__(1024) void seg_prep(
    const int* __restrict__ lab, int* __restrict__ streamTok, int* __restrict__ cumArr,
    int* __restrict__ meta, int* __restrict__ rowC, int* __restrict__ rowStart,
    int* __restrict__ mapArr)
{
    __shared__ int sM[1024], sB[1024];
    __shared__ int sRowC[64], sRowStart[64];
    __shared__ int sIdx0;
    int t = threadIdx.x;
    if (t == 0) sIdx0 = 0x7fffffff;
    int base = t * 32;
    int mc = 0, bc = 0;
    for (int i = 0; i < 32; ++i) { int v = lab[base + i]; mc += (v != 0); bc += (v == 1); }
    sM[t] = mc; sB[t] = bc; __syncthreads();
    for (int off = 1; off < 1024; off <<= 1) {
        int vm = 0, vb = 0;
        if (t >= off) { vm = sM[t - off]; vb = sB[t - off]; }
        __syncthreads();
        sM[t] += vm; sB[t] += vb;
        __syncthreads();
    }
    int mBase = sM[t] - mc, bBase = sB[t] - bc;
    int mRun = 0, bRun = 0;
    for (int i = 0; i < 32; ++i) {
        int v = lab[base + i];
        if (v != 0) {
            int q = mBase + mRun;
            streamTok[q] = base + i;
            int isB = (v == 1);
            cumArr[q] = bBase + bRun + isB;
            if (isB && (bBase + bRun) == 0) sIdx0 = q;   // unique thread
            mRun += 1; bRun += isB;
        }
    }
    if ((t & 15) == 0) sRowStart[t >> 4] = bBase;
    __syncthreads();
    if ((t & 15) == 0) {
        int b = t >> 4;
        sRowC[b] = sB[t + 15] - sRowStart[b];
        rowStart[b] = sRowStart[b];
        rowC[b] = sRowC[b];
    }
    if (t == 1023) { meta[0] = sB[1023]; meta[1] = sM[1023]; }
    if (t == 0) meta[2] = (sIdx0 == 0x7fffffff) ? 0 : sIdx0;
    __syncthreads();
    for (int idx = t; idx < 32768; idx += 1024) {
        int b = idx >> 9, j = idx & 511;
        if (j < sRowC[b]) mapArr[sRowStart[b] + j] = idx;
    }
}

__global__ void seg_assign(const int* __restrict__ cumArr, int* __restrict__ segCount,
                           int* __restrict__ segFirst, const int* __restrict__ meta)
{
    int q = blockIdx.x * 256 + threadIdx.x;
    int K = meta[1];
    if (q >= K) return;
    int numB = meta[0], idx0 = meta[2];
    int qq = q + idx0;
    int cumv = (qq < K) ? cumArr[qq] : numB;
    int seg = cumv - 1;
    if (seg >= 0) {
        atomicAdd(&segCount[seg], 1);
        atomicMin(&segFirst[seg], q);
    }
}

// means for segments [s0, s0+8192) from bf16 hidden -> bf16 chunk rows
__global__ __launch_bounds__(256) void seg_means(
    const unsigned short* __restrict__ hiddenB, const int* __restrict__ streamTok,
    const int* __restrict__ segCount, const int* __restrict__ segFirst,
    const int* __restrict__ meta, unsigned short* __restrict__ means, int s0)
{
    int s = s0 + blockIdx.x;
    if (s >= meta[0]) return;
    int t = threadIdx.x;
    float a0 = 0.f, a1 = 0.f, a2 = 0.f;
    int cnt = segCount[s];
    if (cnt > 0) {
        int q0 = segFirst[s];
        for (int i = 0; i < cnt; ++i) {
            const unsigned short* hr = hiddenB + (size_t)streamTok[q0 + i] * 768;
            a0 += bf2f(hr[t]); a1 += bf2f(hr[t + 256]); a2 += bf2f(hr[t + 512]);
        }
        float fc = (float)cnt;
        a0 /= fc; a1 /= fc; a2 /= fc;
    }
    size_t o = (size_t)(s - s0) * 768;
    means[o + t] = f2bf(a0); means[o + t + 256] = f2bf(a1); means[o + t + 512] = f2bf(a2);
}

// ---------- in-place row log_softmax over 1000 cols + constant fill ----------
__global__ __launch_bounds__(256) void softmax_rows(float* __restrict__ out,
                                                    const int* __restrict__ rowC)
{
    int v = blockIdx.x;
    int b = v >> 9, j = v & 511;
    int t = threadIdx.x;
    float* row = out + (size_t)v * 1000;
    if (j >= rowC[b]) {
        for (int e = t; e < 1000; e += 256) row[e] = -6.907755278982137f;
        return;
    }
    __shared__ float red[256];
    float x0 = row[t];
    float x1 = row[t + 256];
    float x2 = row[t + 512];
    bool has3 = (t + 768) < 1000;
    float x3 = has3 ? row[t + 768] : -1e30f;
    float mx = fmaxf(fmaxf(x0, x1), fmaxf(x2, x3));
    red[t] = mx; __syncthreads();
    for (int st = 128; st > 0; st >>= 1) { if (t < st) red[t] = fmaxf(red[t], red[t + st]); __syncthreads(); }
    float M = red[0]; __syncthreads();
    float sm = expf(x0 - M) + expf(x1 - M) + expf(x2 - M) + (has3 ? expf(x3 - M) : 0.f);
    red[t] = sm; __syncthreads();
    for (int st = 128; st > 0; st >>= 1) { if (t < st) red[t] += red[t + st]; __syncthreads(); }
    float ls = M + logf(red[0]);
    row[t]       = x0 - ls;
    row[t + 256] = x1 - ls;
    row[t + 512] = x2 - ls;
    if (has3) row[t + 768] = x3 - ls;
}

// ---------- launch ----------
extern "C" void kernel_launch(void* const* d_in, const int* in_sizes, int n_in,
                              void* d_out, int out_size, void* d_ws, size_t ws_size,
                              hipStream_t stream)
{
    (void)in_sizes; (void)n_in; (void)out_size; (void)ws_size;
    const int*   labels = (const int*)d_in[0];
    const float* hidden = (const float*)d_in[1];
    const float* ent    = (const float*)d_in[2];
    const float* w1     = (const float*)d_in[3];
    const float* b1     = (const float*)d_in[4];
    const float* w2     = (const float*)d_in[5];
    const float* b2     = (const float*)d_in[6];
    const float* wm     = (const float*)d_in[7];
    const float* wd     = (const float*)d_in[8];

    char* ws = (char*)d_ws;
    size_t off = 0;
    auto alloc = [&](size_t bytes) {
        void* p = ws + off;
        off = (off + bytes + 255) & ~(size_t)255;
        return p;
    };
    int* meta      = (int*)alloc(256);
    int* rowC      = (int*)alloc(256);
    int* rowStart  = (int*)alloc(256);
    int* flagCnt   = (int*)alloc(256);
    int* predLab   = (int*)alloc(32768 * 4);
    int* streamTok = (int*)alloc(32768 * 4);
    int* cumArr    = (int*)alloc(32768 * 4);
    int* segCount  = (int*)alloc(32768 * 4);
    int* segFirst  = (int*)alloc(32768 * 4);
    int* mapArr    = (int*)alloc(32768 * 4);
    int* flagList  = (int*)alloc(FLAG_CAP * 4);
    unsigned short* entB = (unsigned short*)alloc((size_t)1000 * 768 * 2);
    unsigned short* wdT  = (unsigned short*)alloc((size_t)300 * 768 * 2);
    unsigned short* pd   = (unsigned short*)alloc((size_t)1000 * 320 * 2);
    unsigned short* wmP  = (unsigned short*)alloc((size_t)768 * 320 * 2);
    unsigned short* W2t  = (unsigned short*)alloc((size_t)1000 * 768 * 2);
    unsigned short* w1T  = (unsigned short*)alloc((size_t)768 * 768 * 2);
    unsigned short* hiddenB = (unsigned short*)alloc((size_t)32768 * 768 * 2);   // 48 MB
    float* part  = (float*)alloc((size_t)32768 * 3 * 4);
    float* partF = (float*)alloc((size_t)12 * FLAG_CAP * 3 * 4);
    float* Af    = (float*)alloc((size_t)FLAG_CAP * 768 * 4);                    // 25 MB
    unsigned short* meansChunk = (unsigned short*)alloc((size_t)8192 * 768 * 2); // 12.6 MB

    float* out0 = (float*)d_out;
    float* out1 = out0 + 98304;
    float* out2 = out1 + (size_t)32768 * 1000;

    // ---- prep ----
    hipMemsetAsync(pd, 0, (size_t)1000 * 320 * 2, stream);
    hipMemsetAsync(wmP, 0, (size_t)768 * 320 * 2, stream);
    hipMemsetAsync(part, 0, (size_t)32768 * 3 * 4, stream);
    hipMemsetAsync(flagCnt, 0, 4, stream);
    cast_bf16_v4<<<750, 256, 0, stream>>>(ent, entB, 192000);
    cast_bf16_v4<<<24576, 256, 0, stream>>>(hidden, hiddenB, 6291456);
    transpose_cast<<<dim3(10, 24), dim3(32, 8), 0, stream>>>(wd, wdT, 768, 300);
    transpose_cast<<<dim3(24, 24), dim3(32, 8), 0, stream>>>(w1, w1T, 768, 768);
    cast_pad<<<900, 256, 0, stream>>>(wm, wmP, 768, 300, 320);
    // pd[e,p] = ent @ wd   (grid x=nt, y=mt)
    gemm_bt<<<dim3(3, 8), 256, 0, stream>>>(entB, wdT, pd, nullptr, nullptr,
                                            nullptr, nullptr, nullptr,
                                            1000, 300, 768, 768, 768, 320, 0, 0);
    // W2t[e,h] = sum_p pd[e,p]*wm[h,p]
    gemm_bt<<<dim3(6, 8), 256, 0, stream>>>(pd, wmP, W2t, nullptr, nullptr,
                                            nullptr, nullptr, nullptr,
                                            1000, 768, 320, 320, 320, 768, 0, 0);

    // ---- h1 path: bf16 MFMA tile-GEMM + fused bio partials, then exact rescue ----
    gemm_bt<<<dim3(6, 256), 256, 0, stream>>>(hiddenB, w1T, nullptr, nullptr, nullptr,
                                              b1, w2, part,
                                              32768, 768, 768, 768, 768, 0, 3, 0);
    bio_final2<<<128, 256, 0, stream>>>(part, b2, out0, predLab, flagCnt, flagList);
    gather_rows<<<FLAG_CAP, 256, 0, stream>>>(hidden, flagList, flagCnt, Af);
    h1_bio_gemm<<<dim3(FLAG_CAP / 64, 12), dim3(16, 16), 0, stream>>>(
        Af, w1, b1, w2, partF, flagCnt, FLAG_CAP * 3);
    bio_final_fix<<<FLAG_CAP / 256, 256, 0, stream>>>(partF, b2, flagList, flagCnt,
                                                      predLab, FLAG_CAP * 3);

    // ---- per label set: true labels then predicted labels ----
    for (int s = 0; s < 2; ++s) {
        const int* lab = (s == 0) ? labels : predLab;
        float* outS = (s == 0) ? out1 : out2;
        seg_init<<<128, 256, 0, stream>>>(segCount, segFirst);
        seg_prep<<<1, 1024, 0, stream>>>(lab, streamTok, cumArr, meta, rowC, rowStart, mapArr);
        seg_assign<<<128, 256, 0, stream>>>(cumArr, segCount, segFirst, meta);
        for (int c = 0; c < 4; ++c) {
            int s0 = c * 8192;
            seg_means<<<8192, 256, 0, stream>>>(hiddenB, streamTok, segCount, segFirst,
                                                meta, meansChunk, s0);
            gemm_bt<<<dim3(8, 64), 256, 0, stream>>>(meansChunk, W2t, outS, meta, mapArr,
                                                     nullptr, nullptr, nullptr,
                                                     0, 1000, 768, 768, 768, 1000, 2, s0);
        }
        softmax_rows<<<32768, 256, 0, stream>>>(outS, rowC);
    }
}